// Round 7
// baseline (267.552 us; speedup 1.0000x reference)
//
#include <hip/hip_runtime.h>
#include <math.h>

#define TOK 16384
#define DD  2048
#define EE  64
#define MT  16           // tokens per block -> grid 1024 = 4 blocks/CU
#define BK  32           // k per chunk
#define NKC 32           // chunks per K-half (split-K = 2, each half 1024)
#define LDA 40           // halves per token row in LDS (80B stride, <=2-way conflicts)

typedef _Float16 half4v __attribute__((ext_vector_type(4)));
typedef _Float16 half8  __attribute__((ext_vector_type(8)));
typedef float    floatx4 __attribute__((ext_vector_type(4)));

// ---- W pre-split: f32 -> (hi,lo) f16, frag-major layout ----
// wf frag index ((ct*64+kcg)*2+s)*64+lane, 8 halves each.
// ct 0..3 = gate col-tiles (cols (ct&3)*16+cl), ct 4..7 = noise col-tiles.
__global__ void build_wf(const float* __restrict__ Wg, const float* __restrict__ Wn,
                         _Float16* __restrict__ wf) {
  int tid  = blockIdx.x * 256 + threadIdx.x;   // 32768 threads
  int lane = tid & 63;
  int kc   = (tid >> 6) & 63;
  int ct   = tid >> 12;                        // 0..7
  int col  = (ct & 3) * 16 + (lane & 15);
  int k    = kc * 32 + (lane >> 4) * 8;
  const float* W = (ct < 4) ? Wg : Wn;
  const float* src = W + (size_t)col * DD + k;
  float4 a = *reinterpret_cast<const float4*>(src);
  float4 b = *reinterpret_cast<const float4*>(src + 4);
  float v[8] = {a.x, a.y, a.z, a.w, b.x, b.y, b.z, b.w};
  half8 hi, lo;
#pragma unroll
  for (int j = 0; j < 8; ++j) {
    _Float16 h = (_Float16)v[j];
    hi[j] = h;
    lo[j] = (_Float16)(v[j] - (float)h);
  }
  size_t base = (((size_t)(ct * 64 + kc) * 2 + 0) * 64 + lane) * 8;
  *reinterpret_cast<half8*>(wf + base)       = hi;
  *reinterpret_cast<half8*>(wf + base + 512) = lo;
}

// Block 256 thr = 4 waves: wave w -> ch=w&1 (expert cols [ch*32,+32), gate AND
// noise lane-paired), kh=w>>1 (K-half). 32 barrier rounds; x staged pre-split
// to LDS (coalesced), B streamed to regs (contiguous 1KB loads, L2-shared).
// LDS: xs[2 buf][2 kh][2 plane][16*LDA] halves = 10240 B, union with epilogue:
//   Pacc[16][132] @0 (8448) | Vb[16][66] @10240 | Eb @14464 | isum @18688
//   ti @18752 | tp @18880 -> 19008 B total
__global__ __launch_bounds__(256, 4)
void gating_kernel(const float* __restrict__ x, const float* __restrict__ rn,
                   const _Float16* __restrict__ wf, const float* __restrict__ bg,
                   float* __restrict__ out,
                   float* __restrict__ cnt_g, float* __restrict__ psum_g) {
  __shared__ char smem[19008];
  _Float16* xs  = (_Float16*)smem;             // buf*2560h, kh*1280h, plane*640h
  float*    Pacc= (float*)smem;                // stride 132
  float*    Vb  = (float*)(smem + 10240);      // stride 66
  float*    Eb  = (float*)(smem + 14464);      // stride 66
  float*    isum= (float*)(smem + 18688);
  int*      ti  = (int*)(smem + 18752);
  float*    tp  = (float*)(smem + 18880);

  const int t  = threadIdx.x;
  const int w  = t >> 6;
  const int ch = w & 1;        // col-half: experts [ch*32, +32)
  const int kh = w >> 1;       // K-half
  const int l  = t & 63;
  const int q  = l >> 4;
  const int cl = l & 15;
  const int t0 = blockIdx.x * MT;

  // x staging: 256 thr cover 2 kh x 16 tok x 32 k (one float4 each, coalesced)
  const int skh  = t >> 7;
  const int stok = (t >> 3) & 15;
  const int skf  = (t & 7) * 4;
  const float* xg = x + (size_t)(t0 + stok) * DD + skh * 1024 + skf;
  const int sbase = skh * 1280 + stok * LDA + skf;   // + buf*2560 + plane*640

  const half8* wfp = (const half8*)wf;
  // 4 ct per wave: j=0,1 gate cols (ch*32 + j*16 + cl), j=2,3 noise same cols
  const int cts[4] = {2 * ch, 2 * ch + 1, 4 + 2 * ch, 5 + 2 * ch};

  // epilogue operands (kh=0 waves only)
  float bgv[2] = {0.f, 0.f};
  float rnv[4][2];
#pragma unroll
  for (int r = 0; r < 4; ++r) { rnv[r][0] = 0.f; rnv[r][1] = 0.f; }
  if (kh == 0) {
#pragma unroll
    for (int j = 0; j < 2; ++j) bgv[j] = bg[ch * 32 + j * 16 + cl];
#pragma unroll
    for (int r = 0; r < 4; ++r)
#pragma unroll
      for (int j = 0; j < 2; ++j)
        rnv[r][j] = rn[(size_t)(t0 + q * 4 + r) * EE + ch * 32 + j * 16 + cl];
  }

  floatx4 acc[4];
#pragma unroll
  for (int j = 0; j < 4; ++j) acc[j] = (floatx4)0.f;

  // ---- preamble: stage chunk 0 into buf 0 ----
  {
    float4 a = *reinterpret_cast<const float4*>(xg);
    float v[4] = {a.x, a.y, a.z, a.w};
    half4v hi, lo;
#pragma unroll
    for (int j = 0; j < 4; ++j) {
      _Float16 h = (_Float16)v[j];
      hi[j] = h;
      lo[j] = (_Float16)(v[j] - (float)h);
    }
    *reinterpret_cast<half4v*>(&xs[sbase])       = hi;
    *reinterpret_cast<half4v*>(&xs[sbase + 640]) = lo;
  }

  for (int kc = 0; kc < NKC; ++kc) {
    const int cur = kc & 1;
    const bool more = (kc < NKC - 1);
    // prefetch x chunk kc+1 (HBM: full round of latency cover)
    float4 pa;
    if (more) pa = *reinterpret_cast<const float4*>(xg + (kc + 1) * BK);
    // B for current chunk (L2-shared across all blocks; short latency)
    half8 B[4][2];
    {
      const int kcg = kh * NKC + kc;
#pragma unroll
      for (int j = 0; j < 4; ++j)
#pragma unroll
        for (int s = 0; s < 2; ++s)
          B[j][s] = wfp[((size_t)(cts[j] * 64 + kcg) * 2 + s) * 64 + l];
    }
    __syncthreads();   // xs[cur] staged

    const int abase = cur * 2560 + kh * 1280 + cl * LDA + q * 8;
    half8 Ah = *reinterpret_cast<const half8*>(&xs[abase]);
    half8 Al = *reinterpret_cast<const half8*>(&xs[abase + 640]);
    // split-2 product: hi*hi + hi*lo + lo*hi (12 MFMA)
#pragma unroll
    for (int j = 0; j < 4; ++j)
      acc[j] = __builtin_amdgcn_mfma_f32_16x16x32_f16(Ah, B[j][0], acc[j], 0, 0, 0);
#pragma unroll
    for (int j = 0; j < 4; ++j)
      acc[j] = __builtin_amdgcn_mfma_f32_16x16x32_f16(Ah, B[j][1], acc[j], 0, 0, 0);
#pragma unroll
    for (int j = 0; j < 4; ++j)
      acc[j] = __builtin_amdgcn_mfma_f32_16x16x32_f16(Al, B[j][0], acc[j], 0, 0, 0);

    if (more) {
      float v[4] = {pa.x, pa.y, pa.z, pa.w};
      half4v hi, lo;
#pragma unroll
      for (int j = 0; j < 4; ++j) {
        _Float16 h = (_Float16)v[j];
        hi[j] = h;
        lo[j] = (_Float16)(v[j] - (float)h);
      }
      const int nb = (cur ^ 1) * 2560 + sbase;
      *reinterpret_cast<half4v*>(&xs[nb])       = hi;
      *reinterpret_cast<half4v*>(&xs[nb + 640]) = lo;
    }
  }

  __syncthreads();   // xs dead; smem becomes Pacc/Vb/Eb

  // ---- split-K merge: kh=1 waves -> LDS ----
  if (kh == 1) {
#pragma unroll
    for (int j = 0; j < 4; ++j) {
      const int cf = ((j >> 1) ? 64 : 0) + ch * 32 + (j & 1) * 16 + cl;
#pragma unroll
      for (int r = 0; r < 4; ++r)
        Pacc[(q * 4 + r) * 132 + cf] = acc[j][r];
    }
  }
  __syncthreads();

  if (kh == 0) {
#pragma unroll
    for (int r = 0; r < 4; ++r) {
      const int tk = q * 4 + r;             // C/D layout: row = q*4+r
#pragma unroll
      for (int j = 0; j < 2; ++j) {
        const int cg = ch * 32 + j * 16 + cl;
        float g  = acc[j][r]     + Pacc[tk * 132 + cg]      + bgv[j];
        float h  = acc[j + 2][r] + Pacc[tk * 132 + 64 + cg];
        float sp = (h > 20.f) ? h : log1pf(expf(h));
        float v  = g + rnv[r][j] * (sp + 0.01f);
        Vb[tk * 66 + cg] = v;
        Eb[tk * 66 + cg] = expf(v);
      }
    }
  }
  __syncthreads();

  // ---- per-token top-2 + softmax denom (16 threads) ----
  if (t < MT) {
    float v1 = -1e30f, v2 = -1e30f;
    int   i1 = 0, i2 = 0;
    float s = 0.f;
    for (int e = 0; e < EE; ++e) {
      float v = Vb[t * 66 + e];
      s += Eb[t * 66 + e];
      if (v > v1)      { v2 = v1; i2 = i1; v1 = v; i1 = e; }
      else if (v > v2) { v2 = v;  i2 = e; }
    }
    isum[t] = 1.f / s;
    ti[t * 2 + 0] = i1; ti[t * 2 + 1] = i2;
    float e2 = expf(v2 - v1);
    float dn = 1.f + e2;
    tp[t * 2 + 0] = 1.f / dn;
    tp[t * 2 + 1] = e2 / dn;
  }
  __syncthreads();

  // ---- sparse out: patched zero-fill, coalesced (float4/thread) ----
  {
    const int m  = t >> 4;
    const int c0 = (t & 15) * 4;
    const int i1 = ti[m * 2 + 0], i2 = ti[m * 2 + 1];
    const float p1 = tp[m * 2 + 0], p2 = tp[m * 2 + 1];
    float o[4];
#pragma unroll
    for (int j = 0; j < 4; ++j) {
      const int col = c0 + j;
      o[j] = (col == i1) ? p1 : ((col == i2) ? p2 : 0.f);
    }
    *reinterpret_cast<float4*>(out + (size_t)(t0 + m) * EE + c0) =
        make_float4(o[0], o[1], o[2], o[3]);
  }

  // ---- aux partials: per-expert psum & count ----
  if (t < EE) {
    float s = 0.f;
    int   cn = 0;
#pragma unroll
    for (int m = 0; m < MT; ++m) {
      s  += Eb[m * 66 + t] * isum[m];
      cn += (ti[m * 2 + 0] == t) + (ti[m * 2 + 1] == t);
    }
    atomicAdd(&psum_g[t], s);
    atomicAdd(&cnt_g[t], (float)cn);
  }
}

__global__ void aux_kernel(const float* __restrict__ cnt_g,
                           const float* __restrict__ psum_g,
                           float* __restrict__ out) {
  int e = threadIdx.x;  // 64 lanes, one wave
  float v = cnt_g[e] * psum_g[e];
#pragma unroll
  for (int o = 32; o > 0; o >>= 1) v += __shfl_down(v, o);
  if (e == 0)
    out[(size_t)TOK * EE] = v * ((float)EE / ((float)TOK * (float)TOK));
}

extern "C" void kernel_launch(void* const* d_in, const int* in_sizes, int n_in,
                              void* d_out, int out_size, void* d_ws, size_t ws_size,
                              hipStream_t stream) {
  const float* x  = (const float*)d_in[0];
  const float* rn = (const float*)d_in[1];
  const float* Wg = (const float*)d_in[2];
  const float* bg = (const float*)d_in[3];
  const float* Wn = (const float*)d_in[4];
  float* out    = (float*)d_out;
  float* cnt_g  = (float*)d_ws;
  float* psum_g = cnt_g + EE;
  _Float16* wf  = (_Float16*)((float*)d_ws + 128);   // 1 MiB of pre-split W frags

  hipMemsetAsync(d_ws, 0, 2 * EE * sizeof(float), stream);
  build_wf<<<128, 256, 0, stream>>>(Wg, Wn, wf);
  gating_kernel<<<TOK / MT, 256, 0, stream>>>(x, rn, wf, bg, out, cnt_g, psum_g);
  aux_kernel<<<1, 64, 0, stream>>>(cnt_g, psum_g, out);
}